// Round 7
// baseline (177.015 us; speedup 1.0000x reference)
//
#include <hip/hip_runtime.h>
#include <hip/hip_cooperative_groups.h>
#include <math.h>

namespace cg = cooperative_groups;

#define K_TOP   8
#define EPS_F   1e-8f
#define T_DIM   2048
#define H_DIM   1024
#define NHEADS  16

typedef float f4 __attribute__((ext_vector_type(4)));

// Cooperative 2-phase kernel.
// Phase 1: one wave per PAIR of rows (t,t+1): stream 16 heads x 16KB (nt loads),
//          head-mean in registers, shuffle-only top-8, write w/idx to ws.
// grid.sync()
// Phase 2: gather burst: block bk handles rows [8bk, 8bk+8); mlp is re-fetched
//          once (16 MB) then L2/L3-hot, no concurrent stream to flush it.
__global__ __launch_bounds__(256, 2) void ctma_coop_kernel(
    const float* __restrict__ mlp,   // [B, T, H]
    const float* __restrict__ attn,  // [B, Hh, T, T]
    float* __restrict__ out,         // [B, T, H]
    float* __restrict__ ws_w,        // [rows, 8]
    int*   __restrict__ ws_i)        // [rows, 8]
{
    const int lane  = threadIdx.x & 63;
    const int wv_id = threadIdx.x >> 6;
    const int pair  = blockIdx.x * 4 + wv_id;   // 0..2047
    const int row0  = pair * 2;
    const int b1    = row0 >> 11;

    const f4* a4 = reinterpret_cast<const f4*>(
        attn + (size_t)b1 * NHEADS * T_DIM * T_DIM + (size_t)(row0 & (T_DIM - 1)) * T_DIM);
    const size_t hs4 = (size_t)T_DIM * T_DIM / 4;

    // ---------------- Phase 1: head-mean of 2 rows -> registers ----------------
    float acc[2][32];
    #pragma unroll
    for (int r = 0; r < 2; ++r)
        #pragma unroll
        for (int s = 0; s < 32; ++s) acc[r][s] = 0.0f;

    for (int h = 0; h < NHEADS; ++h) {
        f4 ta[8], tb[8];
        const f4* hp = a4 + (size_t)h * hs4;
        #pragma unroll
        for (int j = 0; j < 8; ++j)
            ta[j] = __builtin_nontemporal_load(&hp[64 * j + lane]);
        #pragma unroll
        for (int j = 0; j < 8; ++j)
            tb[j] = __builtin_nontemporal_load(&hp[512 + 64 * j + lane]);
        #pragma unroll
        for (int j = 0; j < 8; ++j) {
            acc[0][4*j+0] += ta[j].x; acc[0][4*j+1] += ta[j].y;
            acc[0][4*j+2] += ta[j].z; acc[0][4*j+3] += ta[j].w;
            acc[1][4*j+0] += tb[j].x; acc[1][4*j+1] += tb[j].y;
            acc[1][4*j+2] += tb[j].z; acc[1][4*j+3] += tb[j].w;
        }
    }
    const float inv16 = 1.0f / (float)NHEADS;
    #pragma unroll
    for (int r = 0; r < 2; ++r)
        #pragma unroll
        for (int s = 0; s < 32; ++s) acc[r][s] *= inv16;

    // top-8 per row (shuffle-only, lowest-index tie-break), write ws
    #pragma unroll
    for (int r = 0; r < 2; ++r) {
        float mybv = -INFINITY;
        int   mybi = 0x7fffffff;
        #pragma unroll
        for (int s = 0; s < 32; ++s) {
            if (acc[r][s] > mybv) { mybv = acc[r][s]; mybi = 256 * (s >> 2) + 4 * lane + (s & 3); }
        }
        unsigned mask = 0;
        float wvv[K_TOP];
        int   wii[K_TOP];

        for (int k = 0; k < K_TOP; ++k) {
            float bv = mybv;
            int   bi = mybi;
            #pragma unroll
            for (int off = 32; off > 0; off >>= 1) {
                const float ov = __shfl_down(bv, off);
                const int   oi = __shfl_down(bi, off);
                if (ov > bv || (ov == bv && oi < bi)) { bv = ov; bi = oi; }
            }
            bv = __shfl(bv, 0);
            bi = __shfl(bi, 0);
            wvv[k] = bv;
            wii[k] = bi;
            if (lane == ((bi >> 2) & 63)) {
                mask |= 1u << (4 * (bi >> 8) + (bi & 3));
                mybv = -INFINITY;
                mybi = 0x7fffffff;
                #pragma unroll
                for (int s = 0; s < 32; ++s) {
                    const float val = ((mask >> s) & 1u) ? -INFINITY : acc[r][s];
                    if (val > mybv) { mybv = val; mybi = 256 * (s >> 2) + 4 * lane + (s & 3); }
                }
            }
        }

        float wsum = 0.0f;
        #pragma unroll
        for (int k = 0; k < K_TOP; ++k) wsum += wvv[k];
        wsum = fmaxf(wsum, EPS_F);
        const float invs = 1.0f / wsum;

        if (lane < K_TOP) {
            ws_w[(size_t)(row0 + r) * K_TOP + lane] = wvv[lane] * invs;
            ws_i[(size_t)(row0 + r) * K_TOP + lane] = wii[lane];
        }
    }

    // ---------------- grid-wide barrier ----------------
    cg::this_grid().sync();

    // ---------------- Phase 2: gather burst ----------------
    const int tid = threadIdx.x;
    #pragma unroll
    for (int r8 = 0; r8 < 8; ++r8) {
        const int row = blockIdx.x * 8 + r8;
        const int b   = row >> 11;

        float w[K_TOP];
        int   gi[K_TOP];
        #pragma unroll
        for (int k = 0; k < K_TOP; ++k) {
            w[k]  = ws_w[(size_t)row * K_TOP + k];
            gi[k] = ws_i[(size_t)row * K_TOP + k];
        }

        const f4* mlp4 = reinterpret_cast<const f4*>(mlp)
                       + (size_t)b * T_DIM * (H_DIM / 4);
        f4 o = (f4)(0.0f);
        #pragma unroll
        for (int k = 0; k < K_TOP; ++k) {
            const f4 m = mlp4[(size_t)gi[k] * (H_DIM / 4) + tid];
            o += w[k] * m;
        }
        __builtin_nontemporal_store(o,
            reinterpret_cast<f4*>(out) + (size_t)row * (H_DIM / 4) + tid);
    }
}

extern "C" void kernel_launch(void* const* d_in, const int* in_sizes, int n_in,
                              void* d_out, int out_size, void* d_ws, size_t ws_size,
                              hipStream_t stream) {
    const float* mlp  = (const float*)d_in[0];   // [B, T, H] fp32
    const float* attn = (const float*)d_in[1];   // [B, Hh, T, T] fp32
    float* out = (float*)d_out;                  // [B, T, H] fp32

    const int B = in_sizes[0] / (T_DIM * H_DIM); // = 2
    const int rows = B * T_DIM;                  // 4096

    float* ws_w = (float*)d_ws;                          // rows*8 floats (128 KB)
    int*   ws_i = (int*)(ws_w + (size_t)rows * K_TOP);   // rows*8 ints  (128 KB)

    void* args[] = { (void*)&mlp, (void*)&attn, (void*)&out,
                     (void*)&ws_w, (void*)&ws_i };
    hipLaunchCooperativeKernel((void*)ctma_coop_kernel,
                               dim3(rows / 8), dim3(256), args, 0, stream);
}

// Round 8
// 104.698 us; speedup vs baseline: 1.6907x; 1.6907x over previous
//
#include <hip/hip_runtime.h>
#include <math.h>

#define K_TOP   8
#define EPS_F   1e-8f
#define T_DIM   2048
#define H_DIM   1024
#define NHEADS  16

typedef float f4 __attribute__((ext_vector_type(4)));

// One 64-lane wave per row. Packed f4 accumulation (v_pk_add_f32),
// 2-deep head prefetch (16 loads in flight), no mean-scale pass
// (top-k on sums == top-k on means; inv16 folded into renorm).
__global__ __launch_bounds__(256, 3) void ctma_row_kernel(
    const float* __restrict__ mlp,   // [B, T, H]
    const float* __restrict__ attn,  // [B, Hh, T, T]
    float* __restrict__ out)         // [B, T, H]
{
    const int lane  = threadIdx.x & 63;
    const int wv_id = threadIdx.x >> 6;
    const int row   = blockIdx.x * 4 + wv_id;  // b*T + t
    const int b     = row >> 11;
    const int t     = row & (T_DIM - 1);

    const f4* a4 = reinterpret_cast<const f4*>(
        attn + (size_t)b * NHEADS * T_DIM * T_DIM + (size_t)t * T_DIM);
    const size_t hs4 = (size_t)T_DIM * T_DIM / 4;

    // ---------------- Phase 1: head-sum -> f4 registers, double-buffered ----
    f4 accv[8];
    #pragma unroll
    for (int j = 0; j < 8; ++j) accv[j] = (f4)(0.0f);

    f4 tA[8], tB[8];
    {
        const f4* hp = a4;  // head 0
        #pragma unroll
        for (int j = 0; j < 8; ++j)
            tA[j] = __builtin_nontemporal_load(&hp[64 * j + lane]);
    }
    #pragma unroll
    for (int h = 0; h < NHEADS; ++h) {
        if (h + 1 < NHEADS) {
            const f4* hp = a4 + (size_t)(h + 1) * hs4;
            if (h & 1) {
                #pragma unroll
                for (int j = 0; j < 8; ++j)
                    tA[j] = __builtin_nontemporal_load(&hp[64 * j + lane]);
            } else {
                #pragma unroll
                for (int j = 0; j < 8; ++j)
                    tB[j] = __builtin_nontemporal_load(&hp[64 * j + lane]);
            }
        }
        if (h & 1) {
            #pragma unroll
            for (int j = 0; j < 8; ++j) accv[j] += tB[j];
        } else {
            #pragma unroll
            for (int j = 0; j < 8; ++j) accv[j] += tA[j];
        }
    }

    // ---------------- Phase 2: top-8 on sums (== top-8 on means) ----------
    // slot s (0..31): element e = 256*(s>>2) + 4*lane + (s&3), value accv[s>>2][s&3]
    float mybv = -INFINITY;
    int   mybi = 0x7fffffff;
    #pragma unroll
    for (int s = 0; s < 32; ++s) {
        const float val = accv[s >> 2][s & 3];
        if (val > mybv) { mybv = val; mybi = 256 * (s >> 2) + 4 * lane + (s & 3); }
    }
    unsigned mask = 0;

    float wvv[K_TOP];
    int   wii[K_TOP];

    for (int k = 0; k < K_TOP; ++k) {
        float bv = mybv;
        int   bi = mybi;
        #pragma unroll
        for (int off = 32; off > 0; off >>= 1) {
            const float ov = __shfl_down(bv, off);
            const int   oi = __shfl_down(bi, off);
            if (ov > bv || (ov == bv && oi < bi)) { bv = ov; bi = oi; }
        }
        bv = __shfl(bv, 0);
        bi = __shfl(bi, 0);
        wvv[k] = bv;
        wii[k] = bi;
        if (lane == ((bi >> 2) & 63)) {
            mask |= 1u << (4 * (bi >> 8) + (bi & 3));
            mybv = -INFINITY;
            mybi = 0x7fffffff;
            #pragma unroll
            for (int s = 0; s < 32; ++s) {
                const float val = ((mask >> s) & 1u) ? -INFINITY : accv[s >> 2][s & 3];
                if (val > mybv) { mybv = val; mybi = 256 * (s >> 2) + 4 * lane + (s & 3); }
            }
        }
    }

    // renorm: w_k = (sum_k/16) / max(Ssum/16, EPS) = sum_k * (inv16 / denom)
    const float inv16 = 1.0f / (float)NHEADS;
    float wsum = 0.0f;
    #pragma unroll
    for (int k = 0; k < K_TOP; ++k) wsum += wvv[k];
    const float denom = fmaxf(wsum * inv16, EPS_F);
    const float scale = inv16 / denom;

    // ---------------- Phase 3: gather-weighted sum ----------------
    const f4* mlp4 = reinterpret_cast<const f4*>(mlp)
                   + (size_t)b * T_DIM * (H_DIM / 4);
    f4 o[4];
    #pragma unroll
    for (int j = 0; j < 4; ++j) o[j] = (f4)(0.0f);

    #pragma unroll
    for (int k = 0; k < K_TOP; ++k) {
        const float w = wvv[k] * scale;
        const f4* src = mlp4 + (size_t)wii[k] * (H_DIM / 4);
        #pragma unroll
        for (int j = 0; j < 4; ++j) {
            const f4 m = src[lane + 64 * j];
            o[j] += w * m;
        }
    }

    f4* out4 = reinterpret_cast<f4*>(out) + (size_t)row * (H_DIM / 4);
    #pragma unroll
    for (int j = 0; j < 4; ++j)
        __builtin_nontemporal_store(o[j], &out4[lane + 64 * j]);
}

extern "C" void kernel_launch(void* const* d_in, const int* in_sizes, int n_in,
                              void* d_out, int out_size, void* d_ws, size_t ws_size,
                              hipStream_t stream) {
    const float* mlp  = (const float*)d_in[0];   // [B, T, H] fp32
    const float* attn = (const float*)d_in[1];   // [B, Hh, T, T] fp32
    float* out = (float*)d_out;                  // [B, T, H] fp32

    const int B = in_sizes[0] / (T_DIM * H_DIM); // = 2
    const int rows = B * T_DIM;                  // 4096
    const int nblocks = rows / 4;                // 1024 blocks x 4 waves

    ctma_row_kernel<<<nblocks, 256, 0, stream>>>(mlp, attn, out);
}

// Round 9
// 104.616 us; speedup vs baseline: 1.6920x; 1.0008x over previous
//
#include <hip/hip_runtime.h>
#include <math.h>

#define K_TOP   8
#define EPS_F   1e-8f
#define T_DIM   2048
#define H_DIM   1024
#define NHEADS  16

typedef float f4 __attribute__((ext_vector_type(4)));

// One 64-lane wave per row. Packed f4 accumulation, half-head (4xf4)
// double-buffered prefetch to fit 128 VGPRs -> 4 blocks/CU (16 waves/CU).
// Top-k on sums (== top-k on means); inv16 folded into renorm scale.
__global__ __launch_bounds__(256, 4) void ctma_row_kernel(
    const float* __restrict__ mlp,   // [B, T, H]
    const float* __restrict__ attn,  // [B, Hh, T, T]
    float* __restrict__ out)         // [B, T, H]
{
    const int lane  = threadIdx.x & 63;
    const int wv_id = threadIdx.x >> 6;
    const int row   = blockIdx.x * 4 + wv_id;  // b*T + t
    const int b     = row >> 11;
    const int t     = row & (T_DIM - 1);

    const f4* a4 = reinterpret_cast<const f4*>(
        attn + (size_t)b * NHEADS * T_DIM * T_DIM + (size_t)t * T_DIM);
    const size_t hs4 = (size_t)T_DIM * T_DIM / 4;

    // ---------------- Phase 1: head-sum -> f4 registers ----------------
    // 32 half-head chunks; chunk c = (head h = c>>1, half p = c&1).
    // Chunk c covers row elements [p*1024, p*1024+1024): 4 f4 per lane.
    f4 accv[8];
    #pragma unroll
    for (int j = 0; j < 8; ++j) accv[j] = (f4)(0.0f);

    f4 tA[4], tB[4];
    // prefetch chunk 0
    #pragma unroll
    for (int j = 0; j < 4; ++j)
        tA[j] = __builtin_nontemporal_load(&a4[64 * j + lane]);

    #pragma unroll
    for (int c = 0; c < 32; ++c) {
        const int accbase = (c & 1) * 4;  // half p -> accv[4p..4p+3]
        if (c + 1 < 32) {
            const int hn = (c + 1) >> 1;
            const int pn = (c + 1) & 1;
            const f4* hp = a4 + (size_t)hn * hs4 + pn * 256;
            if (c & 1) {
                #pragma unroll
                for (int j = 0; j < 4; ++j)
                    tA[j] = __builtin_nontemporal_load(&hp[64 * j + lane]);
            } else {
                #pragma unroll
                for (int j = 0; j < 4; ++j)
                    tB[j] = __builtin_nontemporal_load(&hp[64 * j + lane]);
            }
        }
        if (c & 1) {
            #pragma unroll
            for (int j = 0; j < 4; ++j) accv[accbase + j] += tB[j];
        } else {
            #pragma unroll
            for (int j = 0; j < 4; ++j) accv[accbase + j] += tA[j];
        }
    }

    // ---------------- Phase 2: top-8 on sums ----------------
    // slot s (0..31): element e = 256*(s>>2) + 4*lane + (s&3), value accv[s>>2][s&3]
    float mybv = -INFINITY;
    int   mybi = 0x7fffffff;
    #pragma unroll
    for (int s = 0; s < 32; ++s) {
        const float val = accv[s >> 2][s & 3];
        if (val > mybv) { mybv = val; mybi = 256 * (s >> 2) + 4 * lane + (s & 3); }
    }
    unsigned mask = 0;

    float wvv[K_TOP];
    int   wii[K_TOP];

    for (int k = 0; k < K_TOP; ++k) {
        float bv = mybv;
        int   bi = mybi;
        #pragma unroll
        for (int off = 32; off > 0; off >>= 1) {
            const float ov = __shfl_down(bv, off);
            const int   oi = __shfl_down(bi, off);
            if (ov > bv || (ov == bv && oi < bi)) { bv = ov; bi = oi; }
        }
        bv = __shfl(bv, 0);
        bi = __shfl(bi, 0);
        wvv[k] = bv;
        wii[k] = bi;
        if (lane == ((bi >> 2) & 63)) {
            mask |= 1u << (4 * (bi >> 8) + (bi & 3));
            mybv = -INFINITY;
            mybi = 0x7fffffff;
            #pragma unroll
            for (int s = 0; s < 32; ++s) {
                const float val = ((mask >> s) & 1u) ? -INFINITY : accv[s >> 2][s & 3];
                if (val > mybv) { mybv = val; mybi = 256 * (s >> 2) + 4 * lane + (s & 3); }
            }
        }
    }

    // renorm: w_k = sum_k * (inv16 / max(sum*inv16, EPS))
    const float inv16 = 1.0f / (float)NHEADS;
    float wsum = 0.0f;
    #pragma unroll
    for (int k = 0; k < K_TOP; ++k) wsum += wvv[k];
    const float denom = fmaxf(wsum * inv16, EPS_F);
    const float scale = inv16 / denom;

    // ---------------- Phase 3: gather-weighted sum ----------------
    const f4* mlp4 = reinterpret_cast<const f4*>(mlp)
                   + (size_t)b * T_DIM * (H_DIM / 4);
    f4 o[4];
    #pragma unroll
    for (int j = 0; j < 4; ++j) o[j] = (f4)(0.0f);

    #pragma unroll
    for (int k = 0; k < K_TOP; ++k) {
        const float w = wvv[k] * scale;
        const f4* src = mlp4 + (size_t)wii[k] * (H_DIM / 4);
        #pragma unroll
        for (int j = 0; j < 4; ++j) {
            const f4 m = src[lane + 64 * j];
            o[j] += w * m;
        }
    }

    f4* out4 = reinterpret_cast<f4*>(out) + (size_t)row * (H_DIM / 4);
    #pragma unroll
    for (int j = 0; j < 4; ++j)
        __builtin_nontemporal_store(o[j], &out4[lane + 64 * j]);
}

extern "C" void kernel_launch(void* const* d_in, const int* in_sizes, int n_in,
                              void* d_out, int out_size, void* d_ws, size_t ws_size,
                              hipStream_t stream) {
    const float* mlp  = (const float*)d_in[0];   // [B, T, H] fp32
    const float* attn = (const float*)d_in[1];   // [B, Hh, T, T] fp32
    float* out = (float*)d_out;                  // [B, T, H] fp32

    const int B = in_sizes[0] / (T_DIM * H_DIM); // = 2
    const int rows = B * T_DIM;                  // 4096
    const int nblocks = rows / 4;                // 1024 blocks x 4 waves

    ctma_row_kernel<<<nblocks, 256, 0, stream>>>(mlp, attn, out);
}